// Round 1
// baseline (93.032 us; speedup 1.0000x reference)
//
#include <hip/hip_runtime.h>
#include <stdint.h>

#define NN 256
#define II 128
#define BATCH 512
#define STEPS 6
#define LOG2E 1.4426950408889634f

__device__ __forceinline__ unsigned short f2bf(float x) {
    unsigned u = __builtin_bit_cast(unsigned, x);
    u += 0x7FFFu + ((u >> 16) & 1u);   // round-to-nearest-even
    return (unsigned short)(u >> 16);
}
__device__ __forceinline__ float bflo(unsigned u) { return __builtin_bit_cast(float, u << 16); }
__device__ __forceinline__ float bfhi(unsigned u) { return __builtin_bit_cast(float, u & 0xFFFF0000u); }

// Pack {sigma, mu} -> pq (bf16 p | bf16 q), {W*erev pairs over i} -> wp (bf16x2).
// p = -log2e * sigma ; q = log2e * sigma * mu ; sigmoid(sigma*(v-mu)) = 1/(1+exp2(p*v+q))
__global__ void pack_weights(const float* __restrict__ sigma, const float* __restrict__ mu,
                             const float* __restrict__ W, const float* __restrict__ erev,
                             unsigned* __restrict__ pq, unsigned* __restrict__ wp, int rows)
{
    int idx = blockIdx.x * blockDim.x + threadIdx.x;
    if (idx >= rows * NN) return;
    int i = idx >> 8, j = idx & (NN - 1);
    float sg = sigma[idx];
    float p = -LOG2E * sg;
    float q =  LOG2E * sg * mu[idx];
    pq[idx] = ((unsigned)f2bf(q) << 16) | (unsigned)f2bf(p);
    if (!(i & 1)) {
        float w0 = W[idx] * erev[idx];
        float w1 = W[idx + NN] * erev[idx + NN];
        wp[(i >> 1) * NN + j] = ((unsigned)f2bf(w1) << 16) | (unsigned)f2bf(w0);
    }
}

// One block = 2 batch rows. 1024 threads: j = tid&255 (output neuron), q = tid>>8 (i-quarter).
template<bool PACKED>
__global__ __launch_bounds__(1024, 4)
void ltc_kernel(const float* __restrict__ inputs, const float* __restrict__ state,
                const float* __restrict__ s_sigma, const float* __restrict__ s_mu,
                const float* __restrict__ s_W, const float* __restrict__ s_erev,
                const float* __restrict__ r_sigma, const float* __restrict__ r_mu,
                const float* __restrict__ r_W, const float* __restrict__ r_erev,
                const unsigned* __restrict__ spq, const unsigned* __restrict__ swp,
                const unsigned* __restrict__ rpq, const unsigned* __restrict__ rwp,
                const float* __restrict__ vleak, const float* __restrict__ gleak,
                const float* __restrict__ cm, float* __restrict__ out)
{
    __shared__ float  v_sh[2][NN];       // current state, both rows
    __shared__ float  x_sh[2][II];       // inputs, both rows
    __shared__ float2 sens_sh[2][NN];    // sensory (num, den) per row
    __shared__ float2 part[8][NN];       // partial sums: [q*2 + r][j]

    const int tid  = threadIdx.x;
    const int j    = tid & (NN - 1);
    const int q    = tid >> 8;           // 0..3
    const int row0 = blockIdx.x * 2;

    // Stage state and inputs
    if (tid < 2 * NN) {
        int r = tid >> 8, c = tid & (NN - 1);
        v_sh[r][c] = state[(row0 + r) * NN + c];
    } else if (tid < 2 * NN + 2 * II) {
        int t = tid - 2 * NN;
        x_sh[t >> 7][t & (II - 1)] = inputs[(row0 + (t >> 7)) * II + (t & (II - 1))];
    }

    // Epilogue constants (threads < 512 only)
    const int r2 = tid >> 8;             // row for epilogue role (valid when tid<512)
    float cmv = 0.f, glvl = 0.f, denb = 0.f;
    if (tid < 512) {
        float c = cm[j], g = gleak[j];
        cmv = c; glvl = g * vleak[j]; denb = c + g;
    }
    __syncthreads();

    // ---- Sensory sweep: i in [q*32, q*32+32) ----
    {
        float sn[2] = {0.f, 0.f}, sd[2] = {0.f, 0.f};
        const int ibase = q * 32;
        #pragma unroll 4
        for (int ip = 0; ip < 16; ++ip) {
            const int i = ibase + ip * 2;
            float p0, q0, p1, q1, w0, w1;
            if (PACKED) {
                unsigned u0 = spq[i * NN + j];
                unsigned u1 = spq[(i + 1) * NN + j];
                unsigned uw = swp[(i >> 1) * NN + j];
                p0 = bflo(u0); q0 = bfhi(u0);
                p1 = bflo(u1); q1 = bfhi(u1);
                w0 = bflo(uw); w1 = bfhi(uw);
            } else {
                int k0 = i * NN + j, k1 = k0 + NN;
                float sg0 = s_sigma[k0], sg1 = s_sigma[k1];
                p0 = -LOG2E * sg0; q0 = LOG2E * sg0 * s_mu[k0];
                p1 = -LOG2E * sg1; q1 = LOG2E * sg1 * s_mu[k1];
                w0 = s_W[k0] * s_erev[k0]; w1 = s_W[k1] * s_erev[k1];
            }
            #pragma unroll
            for (int r = 0; r < 2; ++r) {
                float xa = x_sh[r][i], xb = x_sh[r][i + 1];
                float e0 = __builtin_amdgcn_exp2f(fmaf(p0, xa, q0));
                float e1 = __builtin_amdgcn_exp2f(fmaf(p1, xb, q1));
                float t0 = w0 * __builtin_amdgcn_rcpf(1.f + e0);
                float t1 = w1 * __builtin_amdgcn_rcpf(1.f + e1);
                sn[r] += t0 + t1;
                sd[r] += fabsf(t0) + fabsf(t1);
            }
        }
        part[q * 2 + 0][j] = make_float2(sn[0], sd[0]);
        part[q * 2 + 1][j] = make_float2(sn[1], sd[1]);
    }
    __syncthreads();
    if (tid < 512) {
        float2 a0 = part[0 + r2][j], a1 = part[2 + r2][j], a2 = part[4 + r2][j], a3 = part[6 + r2][j];
        sens_sh[r2][j] = make_float2(a0.x + a1.x + a2.x + a3.x, a0.y + a1.y + a2.y + a3.y);
    }
    __syncthreads();

    // ---- 6 recurrent steps: i in [q*64, q*64+64) ----
    for (int step = 0; step < STEPS; ++step) {
        float rn[2] = {0.f, 0.f}, rd[2] = {0.f, 0.f};
        const int ibase = q * 64;
        #pragma unroll 4
        for (int ip = 0; ip < 32; ++ip) {
            const int i = ibase + ip * 2;
            float p0, q0, p1, q1, w0, w1;
            if (PACKED) {
                unsigned u0 = rpq[i * NN + j];
                unsigned u1 = rpq[(i + 1) * NN + j];
                unsigned uw = rwp[(i >> 1) * NN + j];
                p0 = bflo(u0); q0 = bfhi(u0);
                p1 = bflo(u1); q1 = bfhi(u1);
                w0 = bflo(uw); w1 = bfhi(uw);
            } else {
                int k0 = i * NN + j, k1 = k0 + NN;
                float sg0 = r_sigma[k0], sg1 = r_sigma[k1];
                p0 = -LOG2E * sg0; q0 = LOG2E * sg0 * r_mu[k0];
                p1 = -LOG2E * sg1; q1 = LOG2E * sg1 * r_mu[k1];
                w0 = r_W[k0] * r_erev[k0]; w1 = r_W[k1] * r_erev[k1];
            }
            #pragma unroll
            for (int r = 0; r < 2; ++r) {
                float va = v_sh[r][i], vb = v_sh[r][i + 1];
                float e0 = __builtin_amdgcn_exp2f(fmaf(p0, va, q0));
                float e1 = __builtin_amdgcn_exp2f(fmaf(p1, vb, q1));
                float t0 = w0 * __builtin_amdgcn_rcpf(1.f + e0);
                float t1 = w1 * __builtin_amdgcn_rcpf(1.f + e1);
                rn[r] += t0 + t1;
                rd[r] += fabsf(t0) + fabsf(t1);
            }
        }
        part[q * 2 + 0][j] = make_float2(rn[0], rd[0]);
        part[q * 2 + 1][j] = make_float2(rn[1], rd[1]);
        __syncthreads();

        if (tid < 512) {
            float2 a0 = part[0 + r2][j], a1 = part[2 + r2][j], a2 = part[4 + r2][j], a3 = part[6 + r2][j];
            float wn = a0.x + a1.x + a2.x + a3.x + sens_sh[r2][j].x;
            float wd = a0.y + a1.y + a2.y + a3.y + sens_sh[r2][j].y;
            float vp = v_sh[r2][j];
            float vn = (fmaf(cmv, vp, glvl) + wn) * __builtin_amdgcn_rcpf(denb + wd);
            v_sh[r2][j] = vn;
            if (step == STEPS - 1) {
                out[(row0 + r2) * NN + j] = vn;
                out[BATCH * NN + (row0 + r2) * NN + j] = vn;
            }
        }
        __syncthreads();
    }
}

extern "C" void kernel_launch(void* const* d_in, const int* in_sizes, int n_in,
                              void* d_out, int out_size, void* d_ws, size_t ws_size,
                              hipStream_t stream)
{
    const float* inputs  = (const float*)d_in[0];
    const float* state   = (const float*)d_in[1];
    const float* s_mu    = (const float*)d_in[2];
    const float* s_sigma = (const float*)d_in[3];
    const float* s_W     = (const float*)d_in[4];
    const float* s_erev  = (const float*)d_in[5];
    const float* mu      = (const float*)d_in[6];
    const float* sigma   = (const float*)d_in[7];
    const float* W       = (const float*)d_in[8];
    const float* erev    = (const float*)d_in[9];
    const float* vleak   = (const float*)d_in[10];
    const float* gleak   = (const float*)d_in[11];
    const float* cm      = (const float*)d_in[12];
    float* out = (float*)d_out;

    // ws layout: rpq[65536] u32 | rwp[32768] u32 | spq[32768] u32 | swp[16384] u32
    const size_t need = (65536 + 32768 + 32768 + 16384) * sizeof(unsigned);
    if (ws_size >= need) {
        unsigned* rpq = (unsigned*)d_ws;
        unsigned* rwp = rpq + 65536;
        unsigned* spq = rwp + 32768;
        unsigned* swp = spq + 32768;
        pack_weights<<<NN, 256, 0, stream>>>(sigma, mu, W, erev, rpq, rwp, NN);
        pack_weights<<<II, 256, 0, stream>>>(s_sigma, s_mu, s_W, s_erev, spq, swp, II);
        ltc_kernel<true><<<BATCH / 2, 1024, 0, stream>>>(
            inputs, state, s_sigma, s_mu, s_W, s_erev, sigma, mu, W, erev,
            spq, swp, rpq, rwp, vleak, gleak, cm, out);
    } else {
        ltc_kernel<false><<<BATCH / 2, 1024, 0, stream>>>(
            inputs, state, s_sigma, s_mu, s_W, s_erev, sigma, mu, W, erev,
            nullptr, nullptr, nullptr, nullptr, vleak, gleak, cm, out);
    }
}

// Round 2
// 86.133 us; speedup vs baseline: 1.0801x; 1.0801x over previous
//
#include <hip/hip_runtime.h>
#include <stdint.h>

#define NN 256
#define II 128
#define BATCH 512
#define STEPS 6
#define LOG2E 1.4426950408889634f

typedef float v2f __attribute__((ext_vector_type(2)));

__device__ __forceinline__ unsigned short f2bf(float x) {
    unsigned u = __builtin_bit_cast(unsigned, x);
    u += 0x7FFFu + ((u >> 16) & 1u);   // round-to-nearest-even
    return (unsigned short)(u >> 16);
}
__device__ __forceinline__ float bflo(unsigned u) { return __builtin_bit_cast(float, u << 16); }
__device__ __forceinline__ float bfhi(unsigned u) { return __builtin_bit_cast(float, u & 0xFFFF0000u); }

// Pack per (i-pair, j): uint4 { pq[i], pq[i+1], ws_pair, wa_pair }
// p = -log2e*sigma (bf16, low), q = log2e*sigma*mu (bf16, high)
// ws = bf16(W*erev) pair (i in low, i+1 in high), wa = bf16(|W|) pair.
__global__ void pack4(const float* __restrict__ sigma, const float* __restrict__ mu,
                      const float* __restrict__ W, const float* __restrict__ erev,
                      uint4* __restrict__ out, int rows)
{
    int idx = blockIdx.x * blockDim.x + threadIdx.x;
    if (idx >= (rows / 2) * NN) return;
    int ip = idx >> 8, j = idx & (NN - 1);
    int k0 = (ip * 2) * NN + j, k1 = k0 + NN;
    float sg0 = sigma[k0], sg1 = sigma[k1];
    float p0 = -LOG2E * sg0, q0 = LOG2E * sg0 * mu[k0];
    float p1 = -LOG2E * sg1, q1 = LOG2E * sg1 * mu[k1];
    float w0 = W[k0] * erev[k0], w1 = W[k1] * erev[k1];
    uint4 u;
    u.x = ((unsigned)f2bf(q0) << 16) | (unsigned)f2bf(p0);
    u.y = ((unsigned)f2bf(q1) << 16) | (unsigned)f2bf(p1);
    u.z = ((unsigned)f2bf(w1) << 16) | (unsigned)f2bf(w0);
    u.w = ((unsigned)f2bf(fabsf(w1)) << 16) | (unsigned)f2bf(fabsf(w0));
    out[idx] = u;
}

// ---------------- Packed fast kernel ----------------
// One block = 2 batch rows. 1024 threads: j = tid&255, q = tid>>8 (i-quarter).
__global__ __launch_bounds__(1024, 4)
void ltc_packed(const float* __restrict__ inputs, const float* __restrict__ state,
                const uint4* __restrict__ sw4, const uint4* __restrict__ rw4,
                const float* __restrict__ vleak, const float* __restrict__ gleak,
                const float* __restrict__ cm, float* __restrict__ out)
{
    __shared__ __align__(16) float v_sh[2][NN];
    __shared__ __align__(16) float x_sh[2][II];
    __shared__ float2 sens_sh[2][NN];
    __shared__ float2 part[8][NN];

    const int tid  = threadIdx.x;
    const int j    = tid & (NN - 1);
    const int q    = tid >> 8;           // 0..3
    const int row0 = blockIdx.x * 2;

    if (tid < 2 * NN) {
        int r = tid >> 8, c = tid & (NN - 1);
        v_sh[r][c] = state[(row0 + r) * NN + c];
    } else if (tid < 2 * NN + 2 * II) {
        int t = tid - 2 * NN;
        x_sh[t >> 7][t & (II - 1)] = inputs[(row0 + (t >> 7)) * II + (t & (II - 1))];
    }

    const int r2 = tid >> 8;             // epilogue row (valid when tid<512)
    float cmv = 0.f, glvl = 0.f, denb = 0.f;
    if (tid < 512) {
        float c = cm[j], g = gleak[j];
        cmv = c; glvl = g * vleak[j]; denb = c + g;
    }
    __syncthreads();

    // ---- Sensory sweep: i-pairs [q*16, q*16+16) ----
    {
        v2f sn[2] = {{0.f,0.f},{0.f,0.f}}, sd[2] = {{0.f,0.f},{0.f,0.f}};
        #pragma unroll 4
        for (int ip = 0; ip < 16; ++ip) {
            const int i = (q * 16 + ip) * 2;
            uint4 u = sw4[(q * 16 + ip) * NN + j];
            v2f p01 = {bflo(u.x), bflo(u.y)};
            v2f q01 = {bfhi(u.x), bfhi(u.y)};
            v2f ws  = {bflo(u.z), bfhi(u.z)};
            v2f wa  = {bflo(u.w), bfhi(u.w)};
            #pragma unroll
            for (int r = 0; r < 2; ++r) {
                v2f x01 = *(const v2f*)(&x_sh[r][i]);
                v2f arg = __builtin_elementwise_fma(p01, x01, q01);
                v2f e; e.x = __builtin_amdgcn_exp2f(arg.x); e.y = __builtin_amdgcn_exp2f(arg.y);
                v2f b = e + 1.0f;
                float rr = __builtin_amdgcn_rcpf(b.x * b.y);
                v2f bs = __builtin_shufflevector(b, b, 1, 0);
                v2f rs = {rr, rr};
                v2f ms = ws * bs;
                v2f ma = wa * bs;
                sn[r] = __builtin_elementwise_fma(ms, rs, sn[r]);
                sd[r] = __builtin_elementwise_fma(ma, rs, sd[r]);
            }
        }
        part[q * 2 + 0][j] = make_float2(sn[0].x + sn[0].y, sd[0].x + sd[0].y);
        part[q * 2 + 1][j] = make_float2(sn[1].x + sn[1].y, sd[1].x + sd[1].y);
    }
    __syncthreads();
    if (tid < 512) {
        float2 a0 = part[0 + r2][j], a1 = part[2 + r2][j], a2 = part[4 + r2][j], a3 = part[6 + r2][j];
        sens_sh[r2][j] = make_float2(a0.x + a1.x + a2.x + a3.x, a0.y + a1.y + a2.y + a3.y);
    }
    __syncthreads();

    // ---- 6 recurrent steps: i-pairs [q*32, q*32+32) ----
    for (int step = 0; step < STEPS; ++step) {
        v2f sn[2] = {{0.f,0.f},{0.f,0.f}}, sd[2] = {{0.f,0.f},{0.f,0.f}};
        #pragma unroll 4
        for (int ip = 0; ip < 32; ++ip) {
            const int i = (q * 32 + ip) * 2;
            uint4 u = rw4[(q * 32 + ip) * NN + j];
            v2f p01 = {bflo(u.x), bflo(u.y)};
            v2f q01 = {bfhi(u.x), bfhi(u.y)};
            v2f ws  = {bflo(u.z), bfhi(u.z)};
            v2f wa  = {bflo(u.w), bfhi(u.w)};
            #pragma unroll
            for (int r = 0; r < 2; ++r) {
                v2f v01 = *(const v2f*)(&v_sh[r][i]);
                v2f arg = __builtin_elementwise_fma(p01, v01, q01);
                v2f e; e.x = __builtin_amdgcn_exp2f(arg.x); e.y = __builtin_amdgcn_exp2f(arg.y);
                v2f b = e + 1.0f;
                float rr = __builtin_amdgcn_rcpf(b.x * b.y);
                v2f bs = __builtin_shufflevector(b, b, 1, 0);
                v2f rs = {rr, rr};
                v2f ms = ws * bs;
                v2f ma = wa * bs;
                sn[r] = __builtin_elementwise_fma(ms, rs, sn[r]);
                sd[r] = __builtin_elementwise_fma(ma, rs, sd[r]);
            }
        }
        part[q * 2 + 0][j] = make_float2(sn[0].x + sn[0].y, sd[0].x + sd[0].y);
        part[q * 2 + 1][j] = make_float2(sn[1].x + sn[1].y, sd[1].x + sd[1].y);
        __syncthreads();

        if (tid < 512) {
            float2 a0 = part[0 + r2][j], a1 = part[2 + r2][j], a2 = part[4 + r2][j], a3 = part[6 + r2][j];
            float wn = a0.x + a1.x + a2.x + a3.x + sens_sh[r2][j].x;
            float wd = a0.y + a1.y + a2.y + a3.y + sens_sh[r2][j].y;
            float vp = v_sh[r2][j];
            float vn = (fmaf(cmv, vp, glvl) + wn) * __builtin_amdgcn_rcpf(denb + wd);
            v_sh[r2][j] = vn;
            if (step == STEPS - 1) {
                out[(row0 + r2) * NN + j] = vn;
                out[BATCH * NN + (row0 + r2) * NN + j] = vn;
            }
        }
        __syncthreads();
    }
}

// ---------------- Fallback (no workspace): direct f32 ----------------
__global__ __launch_bounds__(1024, 4)
void ltc_fallback(const float* __restrict__ inputs, const float* __restrict__ state,
                  const float* __restrict__ s_sigma, const float* __restrict__ s_mu,
                  const float* __restrict__ s_W, const float* __restrict__ s_erev,
                  const float* __restrict__ r_sigma, const float* __restrict__ r_mu,
                  const float* __restrict__ r_W, const float* __restrict__ r_erev,
                  const float* __restrict__ vleak, const float* __restrict__ gleak,
                  const float* __restrict__ cm, float* __restrict__ out)
{
    __shared__ float  v_sh[2][NN];
    __shared__ float  x_sh[2][II];
    __shared__ float2 sens_sh[2][NN];
    __shared__ float2 part[8][NN];

    const int tid  = threadIdx.x;
    const int j    = tid & (NN - 1);
    const int q    = tid >> 8;
    const int row0 = blockIdx.x * 2;

    if (tid < 2 * NN) {
        int r = tid >> 8, c = tid & (NN - 1);
        v_sh[r][c] = state[(row0 + r) * NN + c];
    } else if (tid < 2 * NN + 2 * II) {
        int t = tid - 2 * NN;
        x_sh[t >> 7][t & (II - 1)] = inputs[(row0 + (t >> 7)) * II + (t & (II - 1))];
    }

    const int r2 = tid >> 8;
    float cmv = 0.f, glvl = 0.f, denb = 0.f;
    if (tid < 512) {
        float c = cm[j], g = gleak[j];
        cmv = c; glvl = g * vleak[j]; denb = c + g;
    }
    __syncthreads();

    {
        float sn[2] = {0.f, 0.f}, sd[2] = {0.f, 0.f};
        for (int ii = 0; ii < 32; ++ii) {
            const int i = q * 32 + ii;
            int k = i * NN + j;
            float sg = s_sigma[k];
            float p = -LOG2E * sg, qq = LOG2E * sg * s_mu[k];
            float w = s_W[k] * s_erev[k];
            #pragma unroll
            for (int r = 0; r < 2; ++r) {
                float e = __builtin_amdgcn_exp2f(fmaf(p, x_sh[r][i], qq));
                float t = w * __builtin_amdgcn_rcpf(1.f + e);
                sn[r] += t; sd[r] += fabsf(t);
            }
        }
        part[q * 2 + 0][j] = make_float2(sn[0], sd[0]);
        part[q * 2 + 1][j] = make_float2(sn[1], sd[1]);
    }
    __syncthreads();
    if (tid < 512) {
        float2 a0 = part[0 + r2][j], a1 = part[2 + r2][j], a2 = part[4 + r2][j], a3 = part[6 + r2][j];
        sens_sh[r2][j] = make_float2(a0.x + a1.x + a2.x + a3.x, a0.y + a1.y + a2.y + a3.y);
    }
    __syncthreads();

    for (int step = 0; step < STEPS; ++step) {
        float sn[2] = {0.f, 0.f}, sd[2] = {0.f, 0.f};
        for (int ii = 0; ii < 64; ++ii) {
            const int i = q * 64 + ii;
            int k = i * NN + j;
            float sg = r_sigma[k];
            float p = -LOG2E * sg, qq = LOG2E * sg * r_mu[k];
            float w = r_W[k] * r_erev[k];
            #pragma unroll
            for (int r = 0; r < 2; ++r) {
                float e = __builtin_amdgcn_exp2f(fmaf(p, v_sh[r][i], qq));
                float t = w * __builtin_amdgcn_rcpf(1.f + e);
                sn[r] += t; sd[r] += fabsf(t);
            }
        }
        part[q * 2 + 0][j] = make_float2(sn[0], sd[0]);
        part[q * 2 + 1][j] = make_float2(sn[1], sd[1]);
        __syncthreads();

        if (tid < 512) {
            float2 a0 = part[0 + r2][j], a1 = part[2 + r2][j], a2 = part[4 + r2][j], a3 = part[6 + r2][j];
            float wn = a0.x + a1.x + a2.x + a3.x + sens_sh[r2][j].x;
            float wd = a0.y + a1.y + a2.y + a3.y + sens_sh[r2][j].y;
            float vp = v_sh[r2][j];
            float vn = (fmaf(cmv, vp, glvl) + wn) * __builtin_amdgcn_rcpf(denb + wd);
            v_sh[r2][j] = vn;
            if (step == STEPS - 1) {
                out[(row0 + r2) * NN + j] = vn;
                out[BATCH * NN + (row0 + r2) * NN + j] = vn;
            }
        }
        __syncthreads();
    }
}

extern "C" void kernel_launch(void* const* d_in, const int* in_sizes, int n_in,
                              void* d_out, int out_size, void* d_ws, size_t ws_size,
                              hipStream_t stream)
{
    const float* inputs  = (const float*)d_in[0];
    const float* state   = (const float*)d_in[1];
    const float* s_mu    = (const float*)d_in[2];
    const float* s_sigma = (const float*)d_in[3];
    const float* s_W     = (const float*)d_in[4];
    const float* s_erev  = (const float*)d_in[5];
    const float* mu      = (const float*)d_in[6];
    const float* sigma   = (const float*)d_in[7];
    const float* W       = (const float*)d_in[8];
    const float* erev    = (const float*)d_in[9];
    const float* vleak   = (const float*)d_in[10];
    const float* gleak   = (const float*)d_in[11];
    const float* cm      = (const float*)d_in[12];
    float* out = (float*)d_out;

    // ws layout: rw4[(NN/2)*NN] uint4 (512KB) | sw4[(II/2)*NN] uint4 (256KB)
    const size_t need = ((NN / 2) * NN + (II / 2) * NN) * sizeof(uint4);
    if (ws_size >= need) {
        uint4* rw4 = (uint4*)d_ws;
        uint4* sw4 = rw4 + (NN / 2) * NN;
        pack4<<<(NN / 2), 256, 0, stream>>>(sigma, mu, W, erev, rw4, NN);
        pack4<<<(II / 2), 256, 0, stream>>>(s_sigma, s_mu, s_W, s_erev, sw4, II);
        ltc_packed<<<BATCH / 2, 1024, 0, stream>>>(inputs, state, sw4, rw4,
                                                   vleak, gleak, cm, out);
    } else {
        ltc_fallback<<<BATCH / 2, 1024, 0, stream>>>(
            inputs, state, s_sigma, s_mu, s_W, s_erev, sigma, mu, W, erev,
            vleak, gleak, cm, out);
    }
}

// Round 3
// 78.073 us; speedup vs baseline: 1.1916x; 1.1032x over previous
//
#include <hip/hip_runtime.h>
#include <stdint.h>

#define NN 256
#define II 128
#define BATCH 512
#define STEPS 6
#define LOG2E 1.4426950408889634f

typedef _Float16 half_t;
typedef _Float16 h2 __attribute__((ext_vector_type(2)));
typedef float v2f __attribute__((ext_vector_type(2)));

// ---------------- pack: per (quad, tid) entry, f16 params ----------------
// Thread mapping in main kernel: tid in [0,1024), q = tid&3 (i-quarter), j = tid>>2.
// Entry (ip2, tid) holds i = q*(ni/4) + ip2*4 + e, e=0..3, column j.
// pq4[entry].{x,y,z,w} = bitcast(h2{p_e, q_e});  p = -log2e*sigma, q = log2e*sigma*mu
// w2[entry] = { h2{w0,w1}, h2{w2,w3} } with w = W*erev (sign kept; |w| via modifier)
__global__ void pack_f16(const float* __restrict__ sigma, const float* __restrict__ mu,
                         const float* __restrict__ W, const float* __restrict__ erev,
                         uint4* __restrict__ pq4, uint2* __restrict__ w2, int ni)
{
    int gid = blockIdx.x * blockDim.x + threadIdx.x;
    int total = (ni / 16) * 1024;
    if (gid >= total) return;
    int ip2 = gid >> 10, t = gid & 1023;
    int q = t & 3, j = t >> 2;
    int i0 = q * (ni / 4) + ip2 * 4;
    unsigned pw[4];
    half_t wa[4];
    #pragma unroll
    for (int e = 0; e < 4; ++e) {
        int k = (i0 + e) * NN + j;
        float sg = sigma[k];
        h2 pq = { (half_t)(-LOG2E * sg), (half_t)(LOG2E * sg * mu[k]) };
        pw[e] = __builtin_bit_cast(unsigned, pq);
        wa[e] = (half_t)(W[k] * erev[k]);
    }
    pq4[gid] = make_uint4(pw[0], pw[1], pw[2], pw[3]);
    h2 w01 = { wa[0], wa[1] }, w23 = { wa[2], wa[3] };
    w2[gid] = make_uint2(__builtin_bit_cast(unsigned, w01),
                         __builtin_bit_cast(unsigned, w23));
}

__device__ __forceinline__ void proc_pair(unsigned pq0, unsigned pq1, unsigned wp,
                                          float va, float vb, v2f& an, v2f& ad)
{
    h2 P0 = __builtin_bit_cast(h2, pq0);
    h2 P1 = __builtin_bit_cast(h2, pq1);
    h2 Wh = __builtin_bit_cast(h2, wp);
    float e0 = __builtin_amdgcn_exp2f(fmaf((float)P0.x, va, (float)P0.y));
    float e1 = __builtin_amdgcn_exp2f(fmaf((float)P1.x, vb, (float)P1.y));
    float b0 = e0 + 1.f, b1 = e1 + 1.f;
    float rr = __builtin_amdgcn_rcpf(b0 * b1);   // shared reciprocal for the pair
    float u0 = b1 * rr, u1 = b0 * rr;            // u = sigmoid
    float w0 = (float)Wh.x, w1 = (float)Wh.y;
    an.x = fmaf(w0, u0, an.x);
    an.y = fmaf(w1, u1, an.y);
    ad.x = fmaf(fabsf(w0), u0, ad.x);            // abs = free src modifier
    ad.y = fmaf(fabsf(w1), u1, ad.y);
}

// ---------------- main: 1 row/block, 512 blocks, 2 blocks/CU ----------------
__global__ __launch_bounds__(1024, 8)
void ltc_f16(const float* __restrict__ inputs, const float* __restrict__ state,
             const uint4* __restrict__ spq, const uint2* __restrict__ sw,
             const uint4* __restrict__ rpq, const uint2* __restrict__ rw,
             const float* __restrict__ vleak, const float* __restrict__ gleak,
             const float* __restrict__ cm, float* __restrict__ out)
{
    __shared__ __align__(16) float v_sh[2][NN];
    __shared__ __align__(16) float x_sh[II];

    const int tid = threadIdx.x;
    const int q   = tid & 3;
    const int j   = tid >> 2;
    const int row = blockIdx.x;

    if (tid < II) {
        x_sh[tid] = inputs[row * II + tid];
    } else if (tid >= 512 && tid < 512 + NN) {
        v_sh[0][tid - 512] = state[row * NN + (tid - 512)];
    }
    const float c   = cm[j];
    const float g   = gleak[j];
    const float glvl = g * vleak[j];
    const float denb = c + g;
    __syncthreads();

    // ---- sensory sweep: 8 quads, i in [q*32, q*32+32) ----
    float sn, sd;
    {
        v2f an = {0.f, 0.f}, ad = {0.f, 0.f};
        #pragma unroll
        for (int ip2 = 0; ip2 < 8; ++ip2) {
            uint4 u = spq[ip2 * 1024 + tid];
            uint2 w = sw[ip2 * 1024 + tid];
            float4 xv = *(const float4*)&x_sh[q * 32 + ip2 * 4];
            proc_pair(u.x, u.y, w.x, xv.x, xv.y, an, ad);
            proc_pair(u.z, u.w, w.y, xv.z, xv.w, an, ad);
        }
        sn = an.x + an.y;
        sd = ad.x + ad.y;
        sn += __shfl_xor(sn, 1, 64); sn += __shfl_xor(sn, 2, 64);
        sd += __shfl_xor(sd, 1, 64); sd += __shfl_xor(sd, 2, 64);
    }

    // ---- 6 recurrent steps: 16 quads, i in [q*64, q*64+64), 1 barrier/step ----
    int cur = 0;
    for (int step = 0; step < STEPS; ++step) {
        v2f an = {0.f, 0.f}, ad = {0.f, 0.f};
        #pragma unroll 4
        for (int ip2 = 0; ip2 < 16; ++ip2) {
            uint4 u = rpq[ip2 * 1024 + tid];
            uint2 w = rw[ip2 * 1024 + tid];
            float4 vv = *(const float4*)&v_sh[cur][q * 64 + ip2 * 4];
            proc_pair(u.x, u.y, w.x, vv.x, vv.y, an, ad);
            proc_pair(u.z, u.w, w.y, vv.z, vv.w, an, ad);
        }
        float rn = an.x + an.y;
        float rd = ad.x + ad.y;
        rn += __shfl_xor(rn, 1, 64); rn += __shfl_xor(rn, 2, 64);
        rd += __shfl_xor(rd, 1, 64); rd += __shfl_xor(rd, 2, 64);

        float wn = rn + sn, wd = rd + sd;
        float vp = v_sh[cur][j];
        float vn = (fmaf(c, vp, glvl) + wn) * __builtin_amdgcn_rcpf(denb + wd);
        if (q == 0) {
            v_sh[cur ^ 1][j] = vn;
            if (step == STEPS - 1) {
                out[row * NN + j] = vn;
                out[BATCH * NN + row * NN + j] = vn;
            }
        }
        __syncthreads();
        cur ^= 1;
    }
}

// ---------------- fallback (no workspace): direct f32, known-correct ----------------
__global__ __launch_bounds__(1024, 4)
void ltc_fallback(const float* __restrict__ inputs, const float* __restrict__ state,
                  const float* __restrict__ s_sigma, const float* __restrict__ s_mu,
                  const float* __restrict__ s_W, const float* __restrict__ s_erev,
                  const float* __restrict__ r_sigma, const float* __restrict__ r_mu,
                  const float* __restrict__ r_W, const float* __restrict__ r_erev,
                  const float* __restrict__ vleak, const float* __restrict__ gleak,
                  const float* __restrict__ cm, float* __restrict__ out)
{
    __shared__ float  v_sh[2][NN];
    __shared__ float  x_sh[2][II];
    __shared__ float2 sens_sh[2][NN];
    __shared__ float2 part[8][NN];

    const int tid  = threadIdx.x;
    const int j    = tid & (NN - 1);
    const int q    = tid >> 8;
    const int row0 = blockIdx.x * 2;

    if (tid < 2 * NN) {
        int r = tid >> 8, cc = tid & (NN - 1);
        v_sh[r][cc] = state[(row0 + r) * NN + cc];
    } else if (tid < 2 * NN + 2 * II) {
        int t = tid - 2 * NN;
        x_sh[t >> 7][t & (II - 1)] = inputs[(row0 + (t >> 7)) * II + (t & (II - 1))];
    }

    const int r2 = tid >> 8;
    float cmv = 0.f, glvl = 0.f, denb = 0.f;
    if (tid < 512) {
        float cc = cm[j], gg = gleak[j];
        cmv = cc; glvl = gg * vleak[j]; denb = cc + gg;
    }
    __syncthreads();

    {
        float sn[2] = {0.f, 0.f}, sd[2] = {0.f, 0.f};
        for (int ii = 0; ii < 32; ++ii) {
            const int i = q * 32 + ii;
            int k = i * NN + j;
            float sg = s_sigma[k];
            float p = -LOG2E * sg, qq = LOG2E * sg * s_mu[k];
            float w = s_W[k] * s_erev[k];
            #pragma unroll
            for (int r = 0; r < 2; ++r) {
                float e = __builtin_amdgcn_exp2f(fmaf(p, x_sh[r][i], qq));
                float t = w * __builtin_amdgcn_rcpf(1.f + e);
                sn[r] += t; sd[r] += fabsf(t);
            }
        }
        part[q * 2 + 0][j] = make_float2(sn[0], sd[0]);
        part[q * 2 + 1][j] = make_float2(sn[1], sd[1]);
    }
    __syncthreads();
    if (tid < 512) {
        float2 a0 = part[0 + r2][j], a1 = part[2 + r2][j], a2 = part[4 + r2][j], a3 = part[6 + r2][j];
        sens_sh[r2][j] = make_float2(a0.x + a1.x + a2.x + a3.x, a0.y + a1.y + a2.y + a3.y);
    }
    __syncthreads();

    for (int step = 0; step < STEPS; ++step) {
        float sn[2] = {0.f, 0.f}, sd[2] = {0.f, 0.f};
        for (int ii = 0; ii < 64; ++ii) {
            const int i = q * 64 + ii;
            int k = i * NN + j;
            float sg = r_sigma[k];
            float p = -LOG2E * sg, qq = LOG2E * sg * r_mu[k];
            float w = r_W[k] * r_erev[k];
            #pragma unroll
            for (int r = 0; r < 2; ++r) {
                float e = __builtin_amdgcn_exp2f(fmaf(p, v_sh[r][i], qq));
                float t = w * __builtin_amdgcn_rcpf(1.f + e);
                sn[r] += t; sd[r] += fabsf(t);
            }
        }
        part[q * 2 + 0][j] = make_float2(sn[0], sd[0]);
        part[q * 2 + 1][j] = make_float2(sn[1], sd[1]);
        __syncthreads();

        if (tid < 512) {
            float2 a0 = part[0 + r2][j], a1 = part[2 + r2][j], a2 = part[4 + r2][j], a3 = part[6 + r2][j];
            float wn = a0.x + a1.x + a2.x + a3.x + sens_sh[r2][j].x;
            float wd = a0.y + a1.y + a2.y + a3.y + sens_sh[r2][j].y;
            float vp = v_sh[r2][j];
            float vn = (fmaf(cmv, vp, glvl) + wn) * __builtin_amdgcn_rcpf(denb + wd);
            v_sh[r2][j] = vn;
            if (step == STEPS - 1) {
                out[(row0 + r2) * NN + j] = vn;
                out[BATCH * NN + (row0 + r2) * NN + j] = vn;
            }
        }
        __syncthreads();
    }
}

extern "C" void kernel_launch(void* const* d_in, const int* in_sizes, int n_in,
                              void* d_out, int out_size, void* d_ws, size_t ws_size,
                              hipStream_t stream)
{
    const float* inputs  = (const float*)d_in[0];
    const float* state   = (const float*)d_in[1];
    const float* s_mu    = (const float*)d_in[2];
    const float* s_sigma = (const float*)d_in[3];
    const float* s_W     = (const float*)d_in[4];
    const float* s_erev  = (const float*)d_in[5];
    const float* mu      = (const float*)d_in[6];
    const float* sigma   = (const float*)d_in[7];
    const float* W       = (const float*)d_in[8];
    const float* erev    = (const float*)d_in[9];
    const float* vleak   = (const float*)d_in[10];
    const float* gleak   = (const float*)d_in[11];
    const float* cm      = (const float*)d_in[12];
    float* out = (float*)d_out;

    // ws layout: rpq4[16384]u4 (256K) | rw2[16384]u2 (128K) | spq4[8192]u4 (128K) | sw2[8192]u2 (64K)
    const size_t need = 16384 * 16 + 16384 * 8 + 8192 * 16 + 8192 * 8;
    if (ws_size >= need) {
        char* p = (char*)d_ws;
        uint4* rpq = (uint4*)p;
        uint2* rw  = (uint2*)(p + 16384 * 16);
        uint4* spq = (uint4*)(p + 16384 * 16 + 16384 * 8);
        uint2* sw  = (uint2*)(p + 16384 * 16 + 16384 * 8 + 8192 * 16);
        pack_f16<<<64, 256, 0, stream>>>(sigma, mu, W, erev, rpq, rw, NN);
        pack_f16<<<32, 256, 0, stream>>>(s_sigma, s_mu, s_W, s_erev, spq, sw, II);
        ltc_f16<<<BATCH, 1024, 0, stream>>>(inputs, state, spq, sw, rpq, rw,
                                            vleak, gleak, cm, out);
    } else {
        ltc_fallback<<<BATCH / 2, 1024, 0, stream>>>(
            inputs, state, s_sigma, s_mu, s_W, s_erev, sigma, mu, W, erev,
            vleak, gleak, cm, out);
    }
}